// Round 6
// baseline (228.502 us; speedup 1.0000x reference)
//
#include <hip/hip_runtime.h>
#include <stdint.h>
#include <stddef.h>

#define S_LEN 2048
#define BATCH 2
#define HID 1024
#define NHEADS 16
#define HDIM 64

typedef __attribute__((ext_vector_type(8))) short short8;
typedef __attribute__((ext_vector_type(4))) short short4v;
typedef __attribute__((ext_vector_type(4))) float float4v;

#define MFMA32(a, b, c) __builtin_amdgcn_mfma_f32_16x16x32_bf16((a), (b), (c), 0, 0, 0)

__device__ __forceinline__ short f2bf(float f) {
  union { float f; uint32_t u; } v; v.f = f;
  uint32_t u = v.u;
  uint32_t r = (u + 0x7fffu + ((u >> 16) & 1u)) >> 16;
  return (short)(uint16_t)r;
}

// pack 4 fp32 -> 4 bf16 lanes j=0..3 (round-half-up)
__device__ __forceinline__ short4v pack_bf16x4(float4v v) {
  union { short4v s; uint32_t u[2]; } U;
  U.u[0] = __builtin_amdgcn_perm(__float_as_uint(v[1]) + 0x8000u,
                                 __float_as_uint(v[0]) + 0x8000u, 0x07060302u);
  U.u[1] = __builtin_amdgcn_perm(__float_as_uint(v[3]) + 0x8000u,
                                 __float_as_uint(v[2]) + 0x8000u, 0x07060302u);
  return U.s;
}

__device__ __forceinline__ void gl_lds16(const void* g, void* l) {
  __builtin_amdgcn_global_load_lds((const __attribute__((address_space(1))) void*)g,
                                   (__attribute__((address_space(3))) void*)l,
                                   16, 0, 0);
}

// ---------------- prep: cast X to bf16, build log2-domain mask bias ----------------
__global__ __launch_bounds__(256) void prep_cast(const float* __restrict__ x,
                                                 const int* __restrict__ mask,
                                                 short* __restrict__ xbf,
                                                 float* __restrict__ maskb) {
  int gid = blockIdx.x * 256 + threadIdx.x;
  const float4v* src = (const float4v*)x;
  float4v v = src[gid];
  short4v o;
  o[0] = f2bf(v[0]); o[1] = f2bf(v[1]); o[2] = f2bf(v[2]); o[3] = f2bf(v[3]);
  ((short4v*)xbf)[gid] = o;
  if (gid < BATCH * S_LEN) maskb[gid] = -14426.9504f * (float)mask[gid];
}

// ---------------- prep: transpose+cast the four weight matrices ----------------
__global__ __launch_bounds__(256) void prep_transpose(const float* __restrict__ w0,
                                                      const float* __restrict__ w1,
                                                      const float* __restrict__ w2,
                                                      const float* __restrict__ w3,
                                                      short* __restrict__ wt) {
  __shared__ short lds[64 * 66];
  int z = blockIdx.z;
  const float* w = (z == 0) ? w0 : (z == 1) ? w1 : (z == 2) ? w2 : w3;
  short* out = wt + (size_t)z * HID * HID;
  int k0 = blockIdx.x * 64, n0 = blockIdx.y * 64;
  int lane = threadIdx.x & 63, wrp = threadIdx.x >> 6;
#pragma unroll
  for (int i = 0; i < 16; i++) {
    int rr = wrp + i * 4;
    lds[lane * 66 + rr] = f2bf(w[(size_t)(k0 + rr) * HID + n0 + lane]);
  }
  __syncthreads();
#pragma unroll
  for (int i = 0; i < 16; i++) {
    int nn = wrp + i * 4;
    out[(size_t)(n0 + nn) * HID + k0 + lane] = lds[nn * 66 + lane];
  }
}

// ---------------- GEMM: C[M x N] = A[M x K] * Bt[N x K]^T + bias ----------------
#define VPS 136  // Vt epilogue LDS row stride (shorts)
template <int BM, int BN, bool TRANS_EP>
__global__ __launch_bounds__(256) void gemm_bt(const short* __restrict__ A,
                                               const short* __restrict__ WTbase,
                                               const float* __restrict__ bq,
                                               const float* __restrict__ bk,
                                               const float* __restrict__ bv,
                                               const float* __restrict__ bo,
                                               short* __restrict__ outQ,
                                               short* __restrict__ outK,
                                               short* __restrict__ outVt,
                                               float* __restrict__ outF,
                                               int mode_base) {
  constexpr int RI = BM / 32;
  constexpr int RJ = BN / 32;
  constexpr int LSZ1 = BM * 128 + BN * 128;
  constexpr int LSZ = (TRANS_EP && LSZ1 < 128 * VPS * 2) ? 128 * VPS * 2 : LSZ1;
  __shared__ __align__(16) char lds[LSZ];
  const int tid = threadIdx.x;
  const int lane = tid & 63, w = tid >> 6;
  const int wm = w & 1, wn = w >> 1;
  const int quad = lane >> 4, l15 = lane & 15;
  const int mode = mode_base + blockIdx.z;
  const short* Bt = WTbase + (size_t)mode * HID * HID;
  const float* bias = (mode == 0) ? bq : (mode == 1) ? bk : (mode == 2) ? bv : bo;
  const int m0 = blockIdx.x * BM, n0 = blockIdx.y * BN;

  float4v acc[RI][RJ];
#pragma unroll
  for (int i = 0; i < RI; i++)
#pragma unroll
    for (int j = 0; j < RJ; j++) acc[i][j] = (float4v)0.0f;

  for (int k0 = 0; k0 < HID; k0 += 64) {
    __syncthreads();
#pragma unroll
    for (int inst = 0; inst < BM / 32; inst++) {
      int p = inst * 256 + tid;
      int r = p >> 3;
      int c = (p & 7) ^ (r & 7);
      gl_lds16(A + (size_t)(m0 + r) * HID + k0 + c * 8, lds + p * 16);
    }
#pragma unroll
    for (int inst = 0; inst < BN / 32; inst++) {
      int p = inst * 256 + tid;
      int r = p >> 3;
      int c = (p & 7) ^ (r & 7);
      gl_lds16(Bt + (size_t)(n0 + r) * HID + k0 + c * 8, lds + BM * 128 + p * 16);
    }
    __syncthreads();
#pragma unroll
    for (int kk = 0; kk < 2; kk++) {
      short8 af[RI], bf[RJ];
#pragma unroll
      for (int i = 0; i < RI; i++) {
        int ra = wm * (BM / 2) + i * 16 + l15;
        af[i] = *(const short8*)(lds + ra * 128 + (((kk * 4 + quad) ^ (ra & 7)) * 16));
      }
#pragma unroll
      for (int j = 0; j < RJ; j++) {
        int rb = wn * (BN / 2) + j * 16 + l15;
        bf[j] = *(const short8*)(lds + BM * 128 + rb * 128 + (((kk * 4 + quad) ^ (rb & 7)) * 16));
      }
#pragma unroll
      for (int i = 0; i < RI; i++)
#pragma unroll
        for (int j = 0; j < RJ; j++)
          acc[i][j] = MFMA32(af[i], bf[j], acc[i][j]);
    }
  }

  if (TRANS_EP && mode == 2) {
    short* eb = (short*)lds;
    __syncthreads();
#pragma unroll
    for (int j = 0; j < RJ; j++) {
      int nl = wn * (BN / 2) + j * 16 + l15;
      float bsv = bias[n0 + nl];
#pragma unroll
      for (int i = 0; i < RI; i++)
#pragma unroll
        for (int r = 0; r < 4; r++) {
          int ml = wm * (BM / 2) + i * 16 + quad * 4 + r;
          eb[nl * VPS + ml] = f2bf(acc[i][j][r] + bsv);
        }
    }
    __syncthreads();
    int row = tid >> 1, half = tid & 1;
    int n = n0 + row, h = n >> 6, d = n & 63;
    int b = m0 >> 11, sc = (m0 & 2047) + half * 64;
    short* dst = outVt + ((size_t)(b * NHEADS + h) * HDIM + d) * S_LEN + sc;
    const short* src = eb + row * VPS + half * 64;
#pragma unroll
    for (int c = 0; c < 8; c++)
      *(short8*)(dst + c * 8) = *(const short8*)(src + c * 8);
    return;
  }

#pragma unroll
  for (int i = 0; i < RI; i++) {
#pragma unroll
    for (int j = 0; j < RJ; j++) {
      int n = n0 + wn * (BN / 2) + j * 16 + l15;
      float bsv = bias[n];
#pragma unroll
      for (int r = 0; r < 4; r++) {
        int m = m0 + wm * (BM / 2) + i * 16 + quad * 4 + r;
        float val = acc[i][j][r] + bsv;
        if (mode == 3) {
          outF[(size_t)m * HID + n] = val;
        } else {
          int b = m >> 11, s = m & 2047, h = n >> 6, d = n & 63;
          short u = f2bf(val);
          if (mode == 0)
            outQ[((size_t)(b * NHEADS + h) * S_LEN + s) * HDIM + d] = u;
          else
            outK[((size_t)(b * NHEADS + h) * S_LEN + s) * HDIM + d] = u;
        }
      }
    }
  }
}

// ---------------- fused attention: 8-wave blocks, MFMA32 PV, low reg state ----
// grid (S/64, NH, B), block 512 = 8 waves: qh = w>>2 (query half, 32 q each),
// kq = w&3 (key quarter, 32 keys each per 128-key tile). QK^T transposed
// (C = K·Q^T) so P's C-layout packs IN-LANE into a 16x16x32 A-frag using a
// permuted key order k = quad*8 + (mt*4+r); V B-frag built with the same
// permutation (two 8B reads from V^T rows) -> PV uses full-K MFMA32.
// Accumulator is only o[2][4] = 32 AGPRs -> 3-4 waves/SIMD.
#define ALDS_V 16384
#define ALDS_L 32768  // lrow partials: 8 waves x 32 floats
#define SCALE_L2E 0.18033688011f  // log2(e)/8

__device__ __forceinline__ float* buf_addr32(float* base, int row, int col) {
  // 32x64 fp32 tile, 16B-chunk xor swizzle on columns
  return base + row * 64 + ((((col >> 2) ^ (row & 15)) << 2) | (col & 3));
}

__global__ __launch_bounds__(512, 2) void attn(const short* __restrict__ Qb,
                                               const short* __restrict__ Kb,
                                               const short* __restrict__ Vt,
                                               const float* __restrict__ maskb,
                                               short* __restrict__ ctx) {
  __shared__ __align__(16) char lds[33792];  // K 16K | V^T 16K | lrow 1K
  const int tid = threadIdx.x, lane = tid & 63, w = tid >> 6;
  const int qh = w >> 2, kq = w & 3;
  const int quad = lane >> 4, l15 = lane & 15;
  const int h = blockIdx.y, b = blockIdx.z, bh = b * NHEADS + h;
  const short* Qh = Qb + (size_t)bh * S_LEN * HDIM;
  const short* Kh = Kb + (size_t)bh * S_LEN * HDIM;
  const short* Vh = Vt + (size_t)bh * HDIM * S_LEN;
  const float* mbase = maskb + b * S_LEN;
  const int qb0 = blockIdx.x * 64;

  // Q B-frags: wave's 2 query tiles (q = qb0 + qh*32 + nt*16 + l15)
  short8 qf[2][2];
#pragma unroll
  for (int nt = 0; nt < 2; nt++)
#pragma unroll
    for (int kk = 0; kk < 2; kk++)
      qf[nt][kk] = *(const short8*)(Qh + (size_t)(qb0 + qh * 32 + nt * 16 + l15) * HDIM + kk * 32 + quad * 8);

  float4v o[2][4];
#pragma unroll
  for (int nt = 0; nt < 2; nt++)
#pragma unroll
    for (int nd = 0; nd < 4; nd++) o[nt][nd] = (float4v)0.0f;
  float lp[2] = {0.0f, 0.0f};

  for (int kb = 0; kb < S_LEN; kb += 128) {
    __syncthreads();
#pragma unroll
    for (int inst = 0; inst < 2; inst++) {
      int p = inst * 512 + tid;
      int r = p >> 3, c = (p & 7) ^ (r & 7);
      gl_lds16(Kh + (size_t)(kb + r) * HDIM + c * 8, lds + p * 16);
      int rv = p >> 4, cv = (p & 15) ^ (rv & 7);
      gl_lds16(Vh + (size_t)rv * S_LEN + kb + cv * 8, lds + ALDS_V + p * 16);
    }
    float4v mb0 = *(const float4v*)(mbase + kb + kq * 32 + quad * 4);
    float4v mb1 = *(const float4v*)(mbase + kb + kq * 32 + 16 + quad * 4);
    __syncthreads();

    // V B-frags in permuted-key order: j<4 -> keys kq*32+quad*4+j, j>=4 -> +16
    short8 vf[4];
    {
      int g0 = kq * 8 + quad, g1 = g0 + 4;  // 8B granule indices in 256B V^T rows
#pragma unroll
      for (int nd = 0; nd < 4; nd++) {
        int rv = nd * 16 + l15;
        union { short8 s8; short4v h[2]; } V;
        V.h[0] = *(const short4v*)(lds + ALDS_V + rv * 256 + (((g0 >> 1) ^ (rv & 7)) * 16) + (g0 & 1) * 8);
        V.h[1] = *(const short4v*)(lds + ALDS_V + rv * 256 + (((g1 >> 1) ^ (rv & 7)) * 16) + (g1 & 1) * 8);
        vf[nd] = V.s8;
      }
    }

    short4v aph[2][2];  // [mt][nt] packed P halves
#pragma unroll
    for (int mt = 0; mt < 2; mt++) {
      int rk = kq * 32 + mt * 16 + l15;
      short8 ka0 = *(const short8*)(lds + rk * 128 + ((quad ^ (rk & 7)) * 16));
      short8 ka1 = *(const short8*)(lds + rk * 128 + (((4 + quad) ^ (rk & 7)) * 16));
      float4v mbv = mt ? mb1 : mb0;
#pragma unroll
      for (int nt = 0; nt < 2; nt++) {
        float4v c = (float4v)0.0f;
        c = MFMA32(ka0, qf[nt][0], c);  // C[key][q]
        c = MFMA32(ka1, qf[nt][1], c);
        float4v ev;
#pragma unroll
        for (int r = 0; r < 4; r++) ev[r] = __builtin_amdgcn_exp2f(c[r] * SCALE_L2E + mbv[r]);
        lp[nt] += (ev[0] + ev[1]) + (ev[2] + ev[3]);
        aph[mt][nt] = pack_bf16x4(ev);
      }
    }
#pragma unroll
    for (int nt = 0; nt < 2; nt++) {
      union { short8 s8; short4v h[2]; } A;
      A.h[0] = aph[0][nt]; A.h[1] = aph[1][nt];
#pragma unroll
      for (int nd = 0; nd < 4; nd++) o[nt][nd] = MFMA32(A.s8, vf[nd], o[nt][nd]);
    }
  }

  // ---- epilogue: reduce 4 key-quarter partials per query half ----
#pragma unroll
  for (int nt = 0; nt < 2; nt++) {
    lp[nt] += __shfl_xor(lp[nt], 16, 64);
    lp[nt] += __shfl_xor(lp[nt], 32, 64);
  }
  float* lrowS = (float*)(lds + ALDS_L);
  __syncthreads();  // loop LDS reads done; safe to reuse
  if (quad == 0) {
#pragma unroll
    for (int nt = 0; nt < 2; nt++) lrowS[w * 32 + nt * 16 + l15] = lp[nt];
  }
  // buf(qh, slot): 32x64 fp32 (8KB each), in the K/V staging area
  float* bufA = (float*)lds + qh * 4096;        // slot 0
  float* bufB = (float*)lds + qh * 4096 + 2048; // slot 1
  if (kq >= 2) {
    float* dst = (kq == 2) ? bufA : bufB;
#pragma unroll
    for (int nt = 0; nt < 2; nt++)
#pragma unroll
      for (int nd = 0; nd < 4; nd++)
#pragma unroll
        for (int r = 0; r < 4; r++)
          *buf_addr32(dst, nt * 16 + quad * 4 + r, nd * 16 + l15) = o[nt][nd][r];
  }
  __syncthreads();
  if (kq < 2) {
    float* src = (kq == 0) ? bufA : bufB;
#pragma unroll
    for (int nt = 0; nt < 2; nt++)
#pragma unroll
      for (int nd = 0; nd < 4; nd++)
#pragma unroll
        for (int r = 0; r < 4; r++)
          o[nt][nd][r] += *buf_addr32(src, nt * 16 + quad * 4 + r, nd * 16 + l15);
  }
  __syncthreads();
  if (kq == 1) {
#pragma unroll
    for (int nt = 0; nt < 2; nt++)
#pragma unroll
      for (int nd = 0; nd < 4; nd++)
#pragma unroll
        for (int r = 0; r < 4; r++)
          *buf_addr32(bufA, nt * 16 + quad * 4 + r, nd * 16 + l15) = o[nt][nd][r];
  }
  __syncthreads();
  if (kq == 0) {
#pragma unroll
    for (int nt = 0; nt < 2; nt++) {
#pragma unroll
      for (int r = 0; r < 4; r++) {
        int lrow = nt * 16 + quad * 4 + r;
        float ls = lrowS[(qh * 4 + 0) * 32 + lrow] + lrowS[(qh * 4 + 1) * 32 + lrow] +
                   lrowS[(qh * 4 + 2) * 32 + lrow] + lrowS[(qh * 4 + 3) * 32 + lrow];
        float inv = 1.0f / ls;
        int q = qb0 + qh * 32 + lrow;
        short* dstp = ctx + (size_t)(b * S_LEN + q) * HID + h * HDIM + l15;
#pragma unroll
        for (int nd = 0; nd < 4; nd++) {
          float val = (o[nt][nd][r] + *buf_addr32(bufA, lrow, nd * 16 + l15)) * inv;
          dstp[nd * 16] = f2bf(val);
        }
      }
    }
  }
}

extern "C" void kernel_launch(void* const* d_in, const int* in_sizes, int n_in,
                              void* d_out, int out_size, void* d_ws, size_t ws_size,
                              hipStream_t stream) {
  const float* hs = (const float*)d_in[0];
  const int* mask = (const int*)d_in[1];
  const float* Wq = (const float*)d_in[2];
  const float* bq = (const float*)d_in[3];
  const float* Wk = (const float*)d_in[4];
  const float* bk = (const float*)d_in[5];
  const float* Wv = (const float*)d_in[6];
  const float* bv = (const float*)d_in[7];
  const float* Wo = (const float*)d_in[8];
  const float* bo = (const float*)d_in[9];
  float* out = (float*)d_out;
  char* ws = (char*)d_ws;

  short* XBF = (short*)(ws);
  short* CTX = (short*)(ws);
  short* WT  = (short*)(ws + (size_t)(8u << 20));
  short* QB  = (short*)(ws + (size_t)(16u << 20));
  short* KB  = (short*)(ws + (size_t)(24u << 20));
  short* VTt = (short*)(ws + (size_t)(32u << 20));
  float* MB  = (float*)(ws + (size_t)(40u << 20));

  prep_cast<<<4096, 256, 0, stream>>>(hs, mask, XBF, MB);
  prep_transpose<<<dim3(16, 16, 4), 256, 0, stream>>>(Wq, Wk, Wv, Wo, WT);
  gemm_bt<128, 128, true><<<dim3(32, 8, 3), 256, 0, stream>>>(XBF, WT, bq, bk, bv, bo, QB, KB, VTt, nullptr, 0);
  attn<<<dim3(32, NHEADS, BATCH), 512, 0, stream>>>(QB, KB, VTt, MB, CTX);
  gemm_bt<64, 128, false><<<dim3(64, 8, 1), 256, 0, stream>>>(CTX, WT, bq, bk, bv, bo, nullptr, nullptr, nullptr, out, 3);
}